// Round 11
// baseline (111.536 us; speedup 1.0000x reference)
//
#include <hip/hip_runtime.h>

constexpr int kB    = 8;
constexpr int kN    = 512;
constexpr int kFIN  = 256;
constexpr int kFOUT = 128;
constexpr int kNE   = 10;
constexpr int kBN   = kB * kN;
constexpr float kALPHA = 0.2f;
constexpr float kNEG   = -9e15f;

typedef __attribute__((ext_vector_type(8))) short bhalf8;
typedef __attribute__((ext_vector_type(4))) float f32x4;

__device__ __forceinline__ unsigned short bf16_trunc(float x) {
    union { float f; unsigned u; } c; c.f = x;
    return (unsigned short)(c.u >> 16);
}
__device__ __forceinline__ float bf16_tof(unsigned short h) {
    union { unsigned u; float f; } c; c.u = ((unsigned)h) << 16;
    return c.f;
}

// ---------------------------------------------------------------------------
// Kernel 0: prep — W pack (bf16 hi/lo, B-fragment order) + emb.a2 table.
//   Wpack[((t*8+ks)*8+nt)*512 + lane*8 + j]
//     = W[t][ks*32+(lane>>4)*8+j][nt*16+(lane&15)]
// Grid 49 x 256: blocks 0..47 pack (12288 fragments), block 48 does ea2.
// ---------------------------------------------------------------------------
__global__ __launch_bounds__(256) void prep_kernel(
    const float* __restrict__ W,          // (T, FIN, FOUT)
    const float* __restrict__ emb,        // (NE+1, FOUT)
    const float* __restrict__ a2,
    unsigned short* __restrict__ Whp,     // (3*8*8*512)
    unsigned short* __restrict__ Wlp,
    float* __restrict__ emb_a2)           // (16)
{
    const int tid = threadIdx.x;
    if (blockIdx.x < 48) {
        const int g    = blockIdx.x * 256 + tid;   // < 12288
        const int lane = g & 63;
        const int nt   = (g >> 6) & 7;
        const int ks   = (g >> 9) & 7;
        const int tt   = g >> 12;                  // 0..2
        const int col  = nt * 16 + (lane & 15);
        const int kb   = ks * 32 + ((lane >> 4) * 8);
        unsigned short hbuf[8], lbuf[8];
        #pragma unroll
        for (int j = 0; j < 8; ++j) {
            const float w = W[((size_t)tt * kFIN + kb + j) * kFOUT + col];
            hbuf[j] = bf16_trunc(w);
            lbuf[j] = bf16_trunc(w - bf16_tof(hbuf[j]));
        }
        const size_t dst = ((size_t)((tt * 8 + ks) * 8 + nt)) * 512 + lane * 8;
        #pragma unroll
        for (int j = 0; j < 8; ++j) { Whp[dst + j] = hbuf[j]; Wlp[dst + j] = lbuf[j]; }
    } else if (tid < 176) {
        const int e = tid >> 4, l = tid & 15;
        float p = 0.f;
        #pragma unroll
        for (int k8 = 0; k8 < 8; ++k8)
            p += emb[e * kFOUT + l + k8 * 16] * a2[l + k8 * 16];
        #pragma unroll
        for (int off = 8; off; off >>= 1) p += __shfl_xor(p, off);
        if (l == 0) emb_a2[e] = p;
    }
}

// ---------------------------------------------------------------------------
// Kernel 1: fused typed projection (split-bf16 MFMA) + mask/bias + s1/s2.
//   Y_t = Xh@Wh + Xh@Wl + Xl@Wh ; h = sum_t mask_t*(Y_t + b_t)
// Grid 128 x 512 thr (8 waves). Block owns 32 rows x all 128 cols x all 3 t.
// Wave (wrow=w&1 -> 16 rows, wcol=w>>1 -> 32 cols): 8 K-steps x 3 t x 2
// n-tiles x 3 split-mfma = 144 MFMA. X converted in-LDS (padded stride 264
// shorts -> 2-way banks = free). Epilogue: h from regs (no y round-trip),
// s1/s2 via LDS stash (reuse of xsh) + shuffle reduce.
// ---------------------------------------------------------------------------
__global__ __launch_bounds__(512) void proj_kernel(
    const float* __restrict__ node_rep,   // (B*N, FIN)
    const float* __restrict__ mask,       // (T, B*N)
    const float* __restrict__ bias,       // (T, FOUT)
    const unsigned short* __restrict__ Whp,
    const unsigned short* __restrict__ Wlp,
    const float* __restrict__ a1,
    const float* __restrict__ a2,
    const float* __restrict__ a_b,
    float* __restrict__ h,                // (B*N, FOUT)
    float* __restrict__ s1,               // (B*N) a_b folded
    float* __restrict__ s2)               // (B*N)
{
    __shared__ short xsh[32][264];        // 16.5 KB (reused as f32 hstash)
    __shared__ short xsl[32][264];        // 16.5 KB

    const int tid  = threadIdx.x;
    const int row0 = blockIdx.x * 32;

    // stage X: f32 -> bf16 hi/lo in LDS (coalesced b128 reads, b64 LDS writes)
    #pragma unroll
    for (int it = 0; it < 4; ++it) {
        const int idx = tid + it * 512;   // < 2048 quads = 32 rows x 64
        const int r = idx >> 6, q = idx & 63;
        const float4 v = *(const float4*)&node_rep[(size_t)(row0 + r) * kFIN + q * 4];
        ushort4 hi, lo;
        hi.x = bf16_trunc(v.x); lo.x = bf16_trunc(v.x - bf16_tof(hi.x));
        hi.y = bf16_trunc(v.y); lo.y = bf16_trunc(v.y - bf16_tof(hi.y));
        hi.z = bf16_trunc(v.z); lo.z = bf16_trunc(v.z - bf16_tof(hi.z));
        hi.w = bf16_trunc(v.w); lo.w = bf16_trunc(v.w - bf16_tof(hi.w));
        *(ushort4*)&xsh[r][q * 4] = hi;
        *(ushort4*)&xsl[r][q * 4] = lo;
    }
    __syncthreads();

    const int wave = tid >> 6, lane = tid & 63;
    const int wrow = wave & 1, wcol = wave >> 1;   // wcol 0..3
    const int arow = wrow * 16 + (lane & 15);
    const int koff = (lane >> 4) * 8;

    f32x4 acc[3][2];
    #pragma unroll
    for (int t = 0; t < 3; ++t)
        #pragma unroll
        for (int nt = 0; nt < 2; ++nt) acc[t][nt] = (f32x4){0,0,0,0};

    #pragma unroll 2
    for (int ks = 0; ks < 8; ++ks) {
        const bhalf8 Ah = *(const bhalf8*)&xsh[arow][ks * 32 + koff];
        const bhalf8 Al = *(const bhalf8*)&xsl[arow][ks * 32 + koff];
        #pragma unroll
        for (int t = 0; t < 3; ++t)
            #pragma unroll
            for (int nt = 0; nt < 2; ++nt) {
                const size_t bw =
                    ((size_t)((t * 8 + ks) * 8 + wcol * 2 + nt)) * 512 + lane * 8;
                const bhalf8 Bh = *(const bhalf8*)(Whp + bw);
                const bhalf8 Bl = *(const bhalf8*)(Wlp + bw);
                acc[t][nt] = __builtin_amdgcn_mfma_f32_16x16x32_bf16(Ah, Bh, acc[t][nt], 0, 0, 0);
                acc[t][nt] = __builtin_amdgcn_mfma_f32_16x16x32_bf16(Ah, Bl, acc[t][nt], 0, 0, 0);
                acc[t][nt] = __builtin_amdgcn_mfma_f32_16x16x32_bf16(Al, Bh, acc[t][nt], 0, 0, 0);
            }
    }
    __syncthreads();                      // xs dead -> reuse xsh as hstash

    float* hstash = (float*)xsh;          // [32][132] floats (16896 B = xsh)

    // epilogue: C/D layout (m89): lane l, reg j -> row (l>>4)*4+j, col l&15
    const int rA = wrow * 16 + ((lane >> 4) * 4);
    const int cA = lane & 15;
    #pragma unroll
    for (int j = 0; j < 4; ++j) {
        const int row = row0 + rA + j;
        const float m0 = mask[row];
        const float m1 = mask[kBN + row];
        const float m2 = mask[2 * kBN + row];
        #pragma unroll
        for (int nt = 0; nt < 2; ++nt) {
            const int col = wcol * 32 + nt * 16 + cA;
            const float hv = m0 * (acc[0][nt][j] + bias[col])
                           + m1 * (acc[1][nt][j] + bias[kFOUT + col])
                           + m2 * (acc[2][nt][j] + bias[2 * kFOUT + col]);
            h[(size_t)row * kFOUT + col] = hv;
            hstash[(rA + j) * 132 + col] = hv;
        }
    }
    __syncthreads();

    // s1/s2: 8 waves x 4 rows
    #pragma unroll
    for (int rr = 0; rr < 4; ++rr) {
        const int r = wave * 4 + rr;
        const float v0 = hstash[r * 132 + lane];
        const float v1 = hstash[r * 132 + 64 + lane];
        float p1 = v0 * a1[lane] + v1 * a1[64 + lane];
        float p2 = v0 * a2[lane] + v1 * a2[64 + lane];
        #pragma unroll
        for (int off = 32; off; off >>= 1) {
            p1 += __shfl_down(p1, off);
            p2 += __shfl_down(p2, off);
        }
        if (lane == 0) {
            s1[row0 + r] = p1 + a_b[0];
            s2[row0 + r] = p2;
        }
    }
}

// ---------------------------------------------------------------------------
// Kernel 2: scores + softmax + histogram + dense attn@h + ELU.
// (UNCHANGED from rounds 9/10 for attribution.)
// ---------------------------------------------------------------------------
__global__ __launch_bounds__(512) void attn_kernel(
    const int*   __restrict__ adj,     // (B, N, N)
    const float* __restrict__ emb,     // (NE+1, FOUT)
    const float* __restrict__ h,       // (B*N, FOUT)
    const float* __restrict__ s1,      // (B*N) a_b folded
    const float* __restrict__ s2,      // (B*N)
    const float* __restrict__ emb_a2g, // (16)
    float* __restrict__ out)           // (B*N, FOUT)
{
    __shared__ float sc[8][kN + 4];
    __shared__ int   adjs[8][kN];
    __shared__ float scT[kN][8];
    __shared__ float wsum[8][16];
    __shared__ float ea2[16];

    const int tid = threadIdx.x;
    const int b   = blockIdx.x >> 6;
    const int i0  = (blockIdx.x & 63) * 8;

    if (tid < 16) ea2[tid] = emb_a2g[tid];
    __syncthreads();

    const int*   adjb = adj + ((size_t)(b * kN + i0)) * kN;
    const float* s2b  = s2 + b * kN;
    #pragma unroll
    for (int it = 0; it < 2; ++it) {
        const int idx = tid + it * 512;
        const int r = idx >> 7, jq = idx & 127;
        const int4   av  = *(const int4*)&adjb[(size_t)r * kN + jq * 4];
        const float4 s2v = *(const float4*)&s2b[jq * 4];
        const float  sr  = s1[b * kN + i0 + r];
        float4 sv; float s;
        s = sr + s2v.x + ea2[av.x]; s = s > 0.f ? s : kALPHA * s; sv.x = av.x > 0 ? s : kNEG;
        s = sr + s2v.y + ea2[av.y]; s = s > 0.f ? s : kALPHA * s; sv.y = av.y > 0 ? s : kNEG;
        s = sr + s2v.z + ea2[av.z]; s = s > 0.f ? s : kALPHA * s; sv.z = av.z > 0 ? s : kNEG;
        s = sr + s2v.w + ea2[av.w]; s = s > 0.f ? s : kALPHA * s; sv.w = av.w > 0 ? s : kNEG;
        *(float4*)&sc[r][jq * 4] = sv;
        *(int4*)&adjs[r][jq * 4] = av;
    }
    __syncthreads();

    {
        const int r = tid >> 6, lane = tid & 63;
        float v[8]; int av[8];
        #pragma unroll
        for (int k = 0; k < 8; ++k) {
            v[k]  = sc[r][lane + k * 64];
            av[k] = adjs[r][lane + k * 64];
        }
        float m = v[0];
        #pragma unroll
        for (int k = 1; k < 8; ++k) m = fmaxf(m, v[k]);
        #pragma unroll
        for (int off = 32; off; off >>= 1) m = fmaxf(m, __shfl_xor(m, off));
        float sum = 0.f;
        #pragma unroll
        for (int k = 0; k < 8; ++k) { v[k] = __expf(v[k] - m); sum += v[k]; }
        #pragma unroll
        for (int off = 32; off; off >>= 1) sum += __shfl_xor(sum, off);
        const float inv = 1.0f / sum;
        #pragma unroll
        for (int k = 0; k < 8; ++k) {
            v[k] *= inv;
            scT[lane + k * 64][r] = v[k];
        }
        #pragma unroll
        for (int e = 1; e <= kNE; ++e) {
            float p = 0.f;
            #pragma unroll
            for (int k = 0; k < 8; ++k) p += (av[k] == e) ? v[k] : 0.f;
            #pragma unroll
            for (int off = 32; off; off >>= 1) p += __shfl_xor(p, off);
            if (lane == 0) wsum[r][e] = p;
        }
    }
    __syncthreads();

    const int f4l = tid & 31;
    const int rg  = (tid >> 5) & 1;
    const int js  = tid >> 6;
    const float* hb  = h + ((size_t)(b * kN + js * 64)) * kFOUT + f4l * 4;
    const float* sct = &scT[js * 64][rg * 4];

    float4 acc0 = {0,0,0,0}, acc1 = {0,0,0,0}, acc2 = {0,0,0,0}, acc3 = {0,0,0,0};
    #pragma unroll 4
    for (int jj = 0; jj < 64; ++jj) {
        const float4 w4 = *(const float4*)&sct[jj * 8];
        const float4 hv = *(const float4*)&hb[(size_t)jj * kFOUT];
        acc0.x = fmaf(w4.x, hv.x, acc0.x); acc0.y = fmaf(w4.x, hv.y, acc0.y);
        acc0.z = fmaf(w4.x, hv.z, acc0.z); acc0.w = fmaf(w4.x, hv.w, acc0.w);
        acc1.x = fmaf(w4.y, hv.x, acc1.x); acc1.y = fmaf(w4.y, hv.y, acc1.y);
        acc1.z = fmaf(w4.y, hv.z, acc1.z); acc1.w = fmaf(w4.y, hv.w, acc1.w);
        acc2.x = fmaf(w4.z, hv.x, acc2.x); acc2.y = fmaf(w4.z, hv.y, acc2.y);
        acc2.z = fmaf(w4.z, hv.z, acc2.z); acc2.w = fmaf(w4.z, hv.w, acc2.w);
        acc3.x = fmaf(w4.w, hv.x, acc3.x); acc3.y = fmaf(w4.w, hv.y, acc3.y);
        acc3.z = fmaf(w4.w, hv.z, acc3.z); acc3.w = fmaf(w4.w, hv.w, acc3.w);
    }
    __syncthreads();

    float* parts_lo = (float*)adjs;
    float* parts_hi = (float*)sc;
    {
        float* pbase = (js < 4) ? parts_lo + js * 1024
                                : parts_hi + (js - 4) * 1024;
        const int rbase = rg * 4;
        *(float4*)&pbase[(rbase + 0) * kFOUT + f4l * 4] = acc0;
        *(float4*)&pbase[(rbase + 1) * kFOUT + f4l * 4] = acc1;
        *(float4*)&pbase[(rbase + 2) * kFOUT + f4l * 4] = acc2;
        *(float4*)&pbase[(rbase + 3) * kFOUT + f4l * 4] = acc3;
    }
    __syncthreads();

    if (tid < 256) {
        const int r  = tid >> 5;
        const int fl = (tid & 31) * 4;
        float4 a = {0,0,0,0};
        #pragma unroll
        for (int p = 0; p < 4; ++p) {
            const float4 v0 = *(const float4*)&parts_lo[p * 1024 + r * kFOUT + fl];
            const float4 v1 = *(const float4*)&parts_hi[p * 1024 + r * kFOUT + fl];
            a.x += v0.x + v1.x; a.y += v0.y + v1.y;
            a.z += v0.z + v1.z; a.w += v0.w + v1.w;
        }
        #pragma unroll
        for (int e = 1; e <= kNE; ++e) {
            const float  wv = wsum[r][e];
            const float4 ev = *(const float4*)&emb[e * kFOUT + fl];
            a.x = fmaf(wv, ev.x, a.x); a.y = fmaf(wv, ev.y, a.y);
            a.z = fmaf(wv, ev.z, a.z); a.w = fmaf(wv, ev.w, a.w);
        }
        a.x = a.x > 0.f ? a.x : expm1f(a.x);
        a.y = a.y > 0.f ? a.y : expm1f(a.y);
        a.z = a.z > 0.f ? a.z : expm1f(a.z);
        a.w = a.w > 0.f ? a.w : expm1f(a.w);
        *(float4*)&out[((size_t)(b * kN + i0 + r)) * kFOUT + fl] = a;
    }
}

// ---------------------------------------------------------------------------
extern "C" void kernel_launch(void* const* d_in, const int* in_sizes, int n_in,
                              void* d_out, int out_size, void* d_ws, size_t ws_size,
                              hipStream_t stream) {
    const float* node_rep = (const float*)d_in[0];
    const float* mask     = (const float*)d_in[1];
    const int*   adj      = (const int*)  d_in[2];
    const float* W        = (const float*)d_in[3];
    const float* bias     = (const float*)d_in[4];
    const float* a1       = (const float*)d_in[5];
    const float* a2       = (const float*)d_in[6];
    const float* a_b      = (const float*)d_in[7];
    const float* emb      = (const float*)d_in[8];
    float* out = (float*)d_out;

    float* fws    = (float*)d_ws;
    float* h      = fws;                           // 524288 f (2 MB)
    float* s1     = h + (size_t)kBN * kFOUT;       // 4096
    float* s2     = s1 + kBN;                      // 4096
    float* emb_a2 = s2 + kBN;                      // 64 (padded)
    unsigned short* Whp = (unsigned short*)(emb_a2 + 64);
    unsigned short* Wlp = Whp + 3 * 8 * 8 * 512;   // 98304 shorts each

    prep_kernel<<<49, 256, 0, stream>>>(W, emb, a2, Whp, Wlp, emb_a2);
    proj_kernel<<<kBN / 32, 512, 0, stream>>>(
        node_rep, mask, bias, Whp, Wlp, a1, a2, a_b, h, s1, s2);
    attn_kernel<<<kBN / 8, 512, 0, stream>>>(
        adj, emb, h, s1, s2, emb_a2, out);
}